// Round 3
// baseline (188.671 us; speedup 1.0000x reference)
//
#include <hip/hip_runtime.h>
#include <cstdint>
#include <cstddef>

typedef short bf16x8 __attribute__((ext_vector_type(8)));
typedef float f32x4 __attribute__((ext_vector_type(4)));

#define EPS 1e-3f

__device__ __forceinline__ short f32_to_bf16s(float f) {
    union { float f; uint32_t u; } v; v.f = f;
    return (short)((v.u + 0x7FFFu + ((v.u >> 16) & 1u)) >> 16);
}

// K0: wt[kp][ci] = bf16(W[ci][kp]) (192x64); at[w][k] = bf16(A[p][v][w]) (32x96, k=p*25+v, zero-padded)
__global__ __launch_bounds__(256) void prep_kernel(const float* __restrict__ A,
                                                   const float* __restrict__ W,
                                                   unsigned short* __restrict__ wt,
                                                   unsigned short* __restrict__ at) {
    int idx = blockIdx.x * 256 + threadIdx.x;
    if (idx < 12288) {
        int kp = idx >> 6, ci = idx & 63;
        wt[idx] = (unsigned short)f32_to_bf16s(W[ci * 192 + kp]);
    } else {
        int j = idx - 12288;
        if (j < 3072) {
            int w = j / 96, k = j - w * 96;
            float val = 0.f;
            if (w < 25 && k < 75) {
                int p = k / 25, v = k - p * 25;
                val = A[(p * 25 + v) * 25 + w];
            }
            at[j] = (unsigned short)f32_to_bf16s(val);
        }
    }
}

// ---- one output c-group: GEMM1 (W^T x xw), stage to Ys slab, GEMM2 (x A), BN+res epilogue
__device__ __forceinline__ void do_group(int g, const unsigned short* __restrict__ wt,
    short* smem, const bf16x8 (&b1)[2][2], const bf16x8 (&b2)[2][3],
    const float* __restrict__ xn, float* __restrict__ outn,
    const float* scs, const float* shs,
    int lg, int wv, int q, int lcol)
{
    bf16x8 a1[3][2];
    #pragma unroll
    for (int mt = 0; mt < 3; ++mt)
        #pragma unroll
        for (int s = 0; s < 2; ++s)
            a1[mt][s] = *(const bf16x8*)(wt + (size_t)(g * 48 + mt * 16 + lcol) * 64 + 32 * s + 8 * q);

    f32x4 acc[3][2];
    #pragma unroll
    for (int mt = 0; mt < 3; ++mt)
        #pragma unroll
        for (int nt = 0; nt < 2; ++nt) acc[mt][nt] = (f32x4){0.f, 0.f, 0.f, 0.f};
    #pragma unroll
    for (int s = 0; s < 2; ++s)
        #pragma unroll
        for (int mt = 0; mt < 3; ++mt) {
            bf16x8 av = a1[mt][s];
            #pragma unroll
            for (int nt = 0; nt < 2; ++nt)
                acc[mt][nt] = __builtin_amdgcn_mfma_f32_16x16x32_bf16(av, b1[nt][s], acc[mt][nt], 0, 0, 0);
        }

    // residual prefetch (same-XCD L2/L3-hot: rows fetched by this block's phase-1)
    const size_t rbase = (size_t)lg * 25;
    float res[2][4];
    #pragma unroll
    for (int nt = 0; nt < 2; ++nt) {
        int w = nt * 16 + lcol;
        bool val = (w < 25) && (lg < 300);
        #pragma unroll
        for (int r = 0; r < 4; ++r) {
            int c = g * 16 + 4 * q + r;
            res[nt][r] = val ? xn[rbase + (size_t)c * 7500 + w] : 0.f;
        }
    }

    // stage D -> own Ys slab (wave-private, no barrier; compiler orders via lgkmcnt)
    #pragma unroll
    for (int mt = 0; mt < 3; ++mt)
        #pragma unroll
        for (int nt = 0; nt < 2; ++nt) {
            int v = nt * 16 + lcol;
            if (v < 25) {
                #pragma unroll
                for (int r = 0; r < 4; ++r) {
                    int kpl = mt * 16 + 4 * q + r;
                    int cl = kpl / 3, p = kpl - 3 * cl;
                    smem[(wv * 16 + cl) * 104 + 25 * p + v] = f32_to_bf16s(acc[mt][nt][r]);
                }
            }
        }

    f32x4 c0 = {0.f, 0.f, 0.f, 0.f}, c1 = {0.f, 0.f, 0.f, 0.f};
    #pragma unroll
    for (int s = 0; s < 3; ++s) {
        bf16x8 a2 = *(const bf16x8*)&smem[(wv * 16 + lcol) * 104 + 32 * s + 8 * q];
        c0 = __builtin_amdgcn_mfma_f32_16x16x32_bf16(a2, b2[0][s], c0, 0, 0, 0);
        c1 = __builtin_amdgcn_mfma_f32_16x16x32_bf16(a2, b2[1][s], c1, 0, 0, 0);
    }

    if (lg < 300) {
        #pragma unroll
        for (int nt = 0; nt < 2; ++nt) {
            int w = nt * 16 + lcol;
            if (w < 25) {
                f32x4 cc = nt ? c1 : c0;
                #pragma unroll
                for (int r = 0; r < 4; ++r) {
                    int c = g * 16 + 4 * q + r;
                    float o = fmaxf(cc[r] * scs[c] + shs[c], 0.f);
                    outn[rbase + (size_t)c * 7500 + w] = fmaxf(o + res[nt][r], 0.f);
                }
            }
        }
    }
}

// Mega v4: v1 structure (1 sample/block, grid 1216) + XCD swizzle + phase-1 MLP unroll.
// All 64 phase-1 loads are issued before any consumption (branchless via clamped
// addresses); 4 serial memory latencies collapse to ~1. Plain stores (v3's nt-store
// write amplification reverted).
__global__ __launch_bounds__(512, 4) void mega_kernel(
    const float* __restrict__ x,
    const unsigned short* __restrict__ wt,
    const unsigned short* __restrict__ at,
    const float* __restrict__ gamma, const float* __restrict__ beta,
    const float* __restrict__ mean, const float* __restrict__ var,
    float* __restrict__ out) {
    // XCD-chunked swizzle: HW round-robins lin over 8 XCDs; bijective since 1216=8*152.
    // XCD k gets logical [152k,152k+152) = n in [4k,4k+4), all ch (consecutive ch adjacent).
    const int lin = blockIdx.x + 38 * blockIdx.y;        // 0..1215
    const int logical = (lin & 7) * 152 + (lin >> 3);
    const int ch = logical % 38;
    const int n  = logical / 38;

    const int l0 = ch * 8;
    const int tid = threadIdx.x;
    const int wv = tid >> 6, lane = tid & 63, q = lane >> 4, lcol = lane & 15;

    __shared__ __align__(16) short smem[13312];   // xwL (13248) aliased with Ys (13312)
    __shared__ float scs[64], shs[64];

    const float* xn  = x   + (size_t)n * 480000;
    float*       outn = out + (size_t)n * 480000;

    if (tid < 64) {
        float sc = gamma[tid] * rsqrtf(var[tid] + EPS);
        scs[tid] = sc;
        shs[tid] = beta[tid] - mean[tid] * sc;
    }

    // Phase 1 (MLP-unrolled): window offsets are wave-uniform (l0 scalar) -> SGPRs.
    int  loff[16];
    bool lok[16];
    #pragma unroll
    for (int i = 0; i < 16; ++i) {
        int l = l0 - 8 + i;
        lok[i]  = (l >= 0) && (l < 300);
        loff[i] = (lok[i] ? l : 0) * 25;
    }

    // Issue all 64 loads (branchless: clamped cidx -> valid addresses; predicate at use)
    float vals[4][16];
    int civ[4], vvv[4];
    bool act[4];
    #pragma unroll
    for (int r = 0; r < 4; ++r) {
        int cidx = tid + r * 512;
        act[r] = cidx < 1600;
        int cc = act[r] ? cidx : 0;
        int ci = cc / 25, v = cc - ci * 25;
        civ[r] = ci; vvv[r] = v;
        const float* xp = xn + (size_t)ci * 7500 + v;
        #pragma unroll
        for (int i = 0; i < 16; ++i) {
            float t = xp[loff[i]];
            vals[r][i] = (act[r] && lok[i]) ? t : 0.f;
        }
    }

    // Consume: running 9-window -> xwL (bf16)
    #pragma unroll
    for (int r = 0; r < 4; ++r) {
        if (act[r]) {
            int ci = civ[r], v = vvv[r];
            float run = vals[r][0] + vals[r][1] + vals[r][2] + vals[r][3]
                      + vals[r][4] + vals[r][5] + vals[r][6] + vals[r][7];
            short* wb = &smem[(ci >> 3) * 1656 + (ci & 7)];
            #pragma unroll
            for (int j = 0; j < 8; ++j) {
                run += vals[r][j + 8];
                wb[(j * 25 + v) * 8] = f32_to_bf16s(run);
                run -= vals[r][j];
            }
        }
    }
    __syncthreads();   // B1: xwL ready

    // b2 fragments (at, L2-resident) — loaded here so phase-1 VGPR pressure stays low
    bf16x8 b2[2][3];
    #pragma unroll
    for (int nt = 0; nt < 2; ++nt)
        #pragma unroll
        for (int s = 0; s < 3; ++s)
            b2[nt][s] = *(const bf16x8*)(at + (size_t)(nt * 16 + lcol) * 96 + 32 * s + 8 * q);

    // b1 fragments: B[k=ci][col], cols wv*25 + nt*16 + lcol (<=206; cols>=200 are
    // stale-but-finite garbage whose D-columns map to w>=25 and are never stored)
    bf16x8 b1[2][2];
    #pragma unroll
    for (int nt = 0; nt < 2; ++nt) {
        int col = wv * 25 + nt * 16 + lcol;
        #pragma unroll
        for (int s = 0; s < 2; ++s)
            b1[nt][s] = *(const bf16x8*)&smem[(4 * s + q) * 1656 + col * 8];
    }
    __syncthreads();   // B2: all xwL reads done; smem becomes Ys

    // Zero own Ys slab pad cols [72,104): wave-private from here on.
    #pragma unroll
    for (int i = lane; i < 512; i += 64) {
        int r = i >> 5, cc = 72 + (i & 31);
        smem[(wv * 16 + r) * 104 + cc] = 0;
    }

    const int lg = l0 + wv;
    #pragma unroll 1
    for (int g = 0; g < 4; ++g)
        do_group(g, wt, smem, b1, b2, xn, outn, scs, shs, lg, wv, q, lcol);
}

extern "C" void kernel_launch(void* const* d_in, const int* in_sizes, int n_in,
                              void* d_out, int out_size, void* d_ws, size_t ws_size,
                              hipStream_t stream) {
    const float* x     = (const float*)d_in[0];
    const float* A     = (const float*)d_in[1];
    const float* W     = (const float*)d_in[2];
    const float* gamma = (const float*)d_in[3];
    const float* beta  = (const float*)d_in[4];
    const float* mean  = (const float*)d_in[5];
    const float* var   = (const float*)d_in[6];
    float* out = (float*)d_out;

    char* ws = (char*)d_ws;
    unsigned short* wt = (unsigned short*)ws;               // 24,576 B
    unsigned short* at = (unsigned short*)(ws + 24576);     // 6,144 B

    prep_kernel<<<60, 256, 0, stream>>>(A, W, wt, at);
    mega_kernel<<<dim3(38, 32), 512, 0, stream>>>(x, wt, at, gamma, beta, mean, var, out);
}